// Round 6
// baseline (706.254 us; speedup 1.0000x reference)
//
#include <hip/hip_runtime.h>
#include <cstdint>

typedef unsigned short u16;
typedef __bf16 bf16x8 __attribute__((ext_vector_type(8)));
typedef float f32x4 __attribute__((ext_vector_type(4)));

// Problem constants
#define B_    16
#define CIN   512
#define COUT  512
#define HW_   64
#define PW    66            // padded width/height
#define XH_ELEMS  ((size_t)B_*PW*PW*CIN)             // 35,684,352 u16 (71.4 MB)
#define WBF_ELEMS ((size_t)16*9*COUT*32)             //  2,359,296 u16 (4.7 MB)

#define WAITV(N)  asm volatile("s_waitcnt vmcnt(" #N ")" ::: "memory")
#define WAITLGKM0 asm volatile("s_waitcnt lgkmcnt(0)" ::: "memory")

__device__ __forceinline__ u16 f2bf(float f) {
  union { float f; unsigned int u; } c; c.f = f;
  unsigned int u = c.u + 0x7fffu + ((c.u >> 16) & 1u);   // RNE
  return (u16)(u >> 16);
}

// async global->LDS, 16B per lane; dest must be wave-uniform-base + lane*16
__device__ __forceinline__ void async16(const void* g, void* l) {
  __builtin_amdgcn_global_load_lds(
      (__attribute__((address_space(1))) unsigned int*)(uintptr_t)g,
      (__attribute__((address_space(3))) unsigned int*)(uintptr_t)l,
      16, 0, 0);
}

// ---------------------------------------------------------------------------
// Kernel 1: zero the padding border of xh[b][66][66][512]
__global__ __launch_bounds__(256) void zero_border(u16* __restrict__ xh) {
  int g = blockIdx.x * 256 + threadIdx.x;
  if (g >= B_ * 260 * 64) return;
  int c8 = g & 63;
  int t  = g >> 6;             // 0 .. 16*260-1
  int b  = t / 260;
  int p  = t - b * 260;
  int rp, cp;
  if (p < 66)       { rp = 0;      cp = p; }
  else if (p < 132) { rp = 65;     cp = p - 66; }
  else {
    int q = p - 132;           // 0..127
    if (q < 64) { rp = q + 1;  cp = 0; }
    else        { rp = q - 63; cp = 65; }
  }
  u16* dst = xh + ((((size_t)b * PW + rp) * PW + cp) << 9) + (c8 << 3);
  *(uint4*)dst = make_uint4(0u, 0u, 0u, 0u);
}

// ---------------------------------------------------------------------------
// Kernel 2: fp32 NCHW -> bf16 padded NHWC, FUSING the modulation scale:
// xh[b][y+1][x+1][i] = bf16( x[b][i][y][x] * C_EQ * s[b][i] ).
__global__ __launch_bounds__(256) void transpose_x(const float* __restrict__ x,
                                                   const float* __restrict__ s,
                                                   u16* __restrict__ xh) {
  const int t   = threadIdx.x;
  const int c8  = t & 7;             // 8-channel group
  const int xq  = (t >> 3) & 15;     // x quad
  const int y01 = t >> 7;            // row within pair
  const int i0  = blockIdx.x * 64;
  const int y   = blockIdx.y * 2 + y01;
  const int b   = blockIdx.z;

  const float C_EQ = 1.4731391e-2f;                 // 1/sqrt(512*9)
  const float4 sA = *(const float4*)(s + (size_t)b * CIN + i0 + c8 * 8);
  const float4 sB = *(const float4*)(s + (size_t)b * CIN + i0 + c8 * 8 + 4);
  float cs[8] = {C_EQ * sA.x, C_EQ * sA.y, C_EQ * sA.z, C_EQ * sA.w,
                 C_EQ * sB.x, C_EQ * sB.y, C_EQ * sB.z, C_EQ * sB.w};

  float4 v[8];
#pragma unroll
  for (int k = 0; k < 8; ++k) {
    const int ci = i0 + c8 * 8 + k;
    v[k] = *(const float4*)(
        x + ((((size_t)b * CIN + ci) * HW_ + y) * HW_) + xq * 4);
  }
#pragma unroll
  for (int j = 0; j < 4; ++j) {
    const int xx = xq * 4 + j;
    u16 oc[8];
#pragma unroll
    for (int k = 0; k < 8; ++k) oc[k] = f2bf(v[k][j] * cs[k]);
    u16* dst = xh + ((((size_t)b * PW + (y + 1)) * PW + (xx + 1)) << 9)
                  + i0 + c8 * 8;
    *(uint4*)dst = *(uint4*)oc;
  }
}

// ---------------------------------------------------------------------------
// Kernel 3a: demod sigma.  One block per o; 16-batch dot in one pass.
__global__ __launch_bounds__(256) void sigma_kernel(const float* __restrict__ w,
                                                    const float* __restrict__ s,
                                                    float* __restrict__ sig) {
  __shared__ float row[CIN * 9];       // 18,432 B
  __shared__ float part[16][4];

  const int o   = blockIdx.x;
  const int tid = threadIdx.x;
  const int wv  = tid >> 6;
  const int lane = tid & 63;
  const float* wrow = w + (size_t)o * (CIN * 9);

#pragma unroll
  for (int it = 0; it < 5; ++it) {
    const int c = it * 256 + tid;
    if (c < 1152) *(float4*)&row[c * 4] = *(const float4*)(wrow + c * 4);
  }
  __syncthreads();

  float q0 = 0.f, q1 = 0.f;
#pragma unroll
  for (int tt = 0; tt < 9; ++tt) {
    const float a = row[(2 * tid) * 9 + tt];
    const float c = row[(2 * tid + 1) * 9 + tt];
    q0 += a * a; q1 += c * c;
  }

  const float C_EQ = 1.4731391e-2f;                 // 1/sqrt(512*9)
#pragma unroll
  for (int b = 0; b < 16; ++b) {
    const float2 sv = *(const float2*)(s + (size_t)b * CIN + 2 * tid);
    float a = q0 * sv.x * sv.x + q1 * sv.y * sv.y;
#pragma unroll
    for (int off = 32; off > 0; off >>= 1) a += __shfl_xor(a, off, 64);
    if (lane == 0) part[b][wv] = a;
  }
  __syncthreads();
  if (tid < 16) {
    const float tot = part[tid][0] + part[tid][1] + part[tid][2] + part[tid][3];
    sig[(size_t)tid * COUT + o] = rsqrtf(tot * (C_EQ * C_EQ) + 1e-8f);
  }
}

// ---------------------------------------------------------------------------
// Kernel 3b: raw-weight layout transform (batch-independent).
// wbf[icc][tap][o][ich] = bf16(w[o][icc*32+ich][tap]).  4.7 MB, L2-resident.
__global__ __launch_bounds__(256) void wlayout(const float* __restrict__ w,
                                               u16* __restrict__ wbf) {
  __shared__ float wld[288][33];     // 38,016 B, transposed slab

  const int tid = threadIdx.x;
  const int icc = blockIdx.x & 15;
  const int oh  = blockIdx.x >> 4;   // 0..15
  const int o0  = oh << 5;           // 32 outputs per block

#pragma unroll
  for (int it = 0; it < 9; ++it) {
    const int c   = it * 256 + tid;      // 0..2303
    const int ol  = c / 72;
    const int col = c - ol * 72;
    const float4 v = *(const float4*)(
        w + (size_t)(o0 + ol) * (CIN * 9) + icc * 288 + col * 4);
#pragma unroll
    for (int j2 = 0; j2 < 4; ++j2) wld[col * 4 + j2][ol] = v[j2];
  }
  __syncthreads();

  const int ol = tid >> 3;
  const int g4 = tid & 7;
#pragma unroll
  for (int tap = 0; tap < 9; ++tap) {
    u16 oc[4];
#pragma unroll
    for (int kk = 0; kk < 4; ++kk)
      oc[kk] = f2bf(wld[(g4 * 4 + kk) * 9 + tap][ol]);
    *(uint2*)(wbf + (((size_t)(icc * 9 + tap) * COUT) + o0 + ol) * 32 + g4 * 4)
        = *(uint2*)oc;
  }
}

// ---------------------------------------------------------------------------
// Kernel 4: implicit-GEMM conv.  Round-6: B single-buffered in LDS +
// register-staged one chunk ahead (T14 issue-early/write-late); A triple-
// buffered async 2-phase-ahead (unchanged, verified).  LDS 49.3 KB ->
// 3 blocks/CU (12 waves/CU) for wave-level MFMA/LDS overlap.
//   vmcnt ledger (per wave, in-flight newest-first at each entry):
//     boundary: A(t0)2+A(t1)2 -> WAITV(4) for breg; WAITV(2) for A(t0)
//     tap1: A(t2)2+B7 younger than A(t1) -> WAITV(9)
//     tap2: B7+A(t3)2 younger than A(t2) -> WAITV(9)
//     tap>=3: A(t+1)2 -> WAITV(2)
#define AS_ELEMS (128 * 32)            // 4096 u16 per A buffer (8 KB)
#define BROWS    (6 * 66)              // 396 rows
#define BS_ELEMS (BROWS * 32)          // 12672 u16 (25.3 KB), single buffer

__device__ __forceinline__ void stage_A(const u16* __restrict__ wb,
                                        u16* dst, int phase, int o0, int tid) {
  const u16* asrc = wb + ((size_t)phase * COUT + o0) * 32;
#pragma unroll
  for (int t = 0; t < 2; ++t) {
    const int id   = t * 256 + tid;
    const int row  = id >> 2;
    const int slot = (id & 3) ^ (row & 3);
    async16(asrc + row * 32 + slot * 8, dst + id * 8);
  }
}

// load next B window (6 rows x 66 x 32ch = 1584 x 16B) into registers
__device__ __forceinline__ void loadB(const u16* __restrict__ xb, int ic,
                                      int y0, int tid, uint4* breg) {
#pragma unroll
  for (int t = 0; t < 6; ++t) {
    const int id = t * 256 + tid;
    breg[t] = *(const uint4*)(
        xb + ((size_t)y0 * PW + (id >> 2)) * CIN + ic * 32 + (id & 3) * 8);
  }
  if (tid < 48) {
    const int id = 1536 + tid;
    breg[6] = *(const uint4*)(
        xb + ((size_t)y0 * PW + (id >> 2)) * CIN + ic * 32 + (id & 3) * 8);
  }
}

// write staged B to LDS with XOR bank-swizzle (write-side; conflict-free)
__device__ __forceinline__ void writeB(u16* Bs, int tid, const uint4* breg) {
#pragma unroll
  for (int t = 0; t < 6; ++t) {
    const int id   = t * 256 + tid;
    const int row  = id >> 2;
    const int slot = (id & 3) ^ (row & 3);
    *(uint4*)&Bs[(row << 5) + slot * 8] = breg[t];
  }
  if (tid < 48) {
    const int id   = 1536 + tid;
    const int row  = id >> 2;
    const int slot = (id & 3) ^ (row & 3);
    *(uint4*)&Bs[(row << 5) + slot * 8] = breg[6];
  }
}

__global__ __launch_bounds__(256, 3) void modconv_mfma(const u16* __restrict__ xh,
                                                       const u16* __restrict__ wbf,
                                                       const float* __restrict__ sig,
                                                       const float* __restrict__ bias,
                                                       float* __restrict__ out) {
  __shared__ u16 As[3 * AS_ELEMS];     // 24 KB   [buf][o_local][ch]
  __shared__ u16 Bs[BS_ELEMS];         // 25.3 KB [row][ch], single buffer

  const int tid  = threadIdx.x;
  const int lane = tid & 63;
  const int wv   = tid >> 6;
  const int l15  = lane & 15;
  const int q    = lane >> 4;
  const int sw15 = l15 & 3;

  const int lin     = blockIdx.x;
  const int logical = ((lin & 7) << 7) + (lin >> 3);
  const int yt = logical & 15;
  const int ot = (logical >> 4) & 3;
  const int b  = logical >> 6;
  const int y0 = yt << 2;
  const int o0 = ot << 7;

  const u16* xb = xh + (size_t)b * (PW * PW * CIN);
  const u16* wb = wbf;                 // shared across batches

  f32x4 acc[8][4];
#pragma unroll
  for (int mi = 0; mi < 8; ++mi)
#pragma unroll
    for (int cg = 0; cg < 4; ++cg) acc[mi][cg] = (f32x4){0.f, 0.f, 0.f, 0.f};

  uint4 breg[7];

  // prologue: B(0) to regs, A(0)->buf0, A(1)->buf1; write B(0) to LDS.
  loadB(xb, 0, y0, tid, breg);
  stage_A(wb, As, 0, o0, tid);
  stage_A(wb, As + AS_ELEMS, 1, o0, tid);
  WAITV(4);                            // breg landed (A0,A1 still flying)
  writeB(Bs, tid, breg);
  WAITLGKM0;

  // ---- main: ic = 0..14 ----
  for (int ic = 0; ic < 15; ++ic) {
#pragma unroll
    for (int tap = 0; tap < 9; ++tap) {
      if (tap == 0) {
        if (ic > 0) {                  // chunk boundary: swap B in place
          __builtin_amdgcn_s_barrier();   // all waves done reading Bs
          WAITV(4);                       // breg (B(ic)) landed
          writeB(Bs, tid, breg);
          WAITLGKM0;
        }
        WAITV(2);                      // A(t0) landed
      } else if (tap == 1 || tap == 2) {
        WAITV(9);
      } else {
        WAITV(2);
      }
      __builtin_amdgcn_s_barrier();
      __builtin_amdgcn_sched_barrier(0);

      const int ky = tap / 3, kx = tap % 3;
      const int aCur = (tap % 3) * AS_ELEMS;
      const int aDst = ((tap + 2) % 3) * AS_ELEMS;
      const int rbbase = (wv + ky) * 66 + kx;

      bf16x8 bfr[4];
#pragma unroll
      for (int cg = 0; cg < 4; ++cg) {
        const int rb = rbbase + cg * 16 + l15;
        bfr[cg] = *(const bf16x8*)&Bs[(rb << 5) + ((q ^ (rb & 3)) << 3)];
      }

      stage_A(wb, As + aDst, ic * 9 + tap + 2, o0, tid);
      if (tap == 0) loadB(xb, ic + 1, y0, tid, breg);   // B(ic+1) -> regs
      __builtin_amdgcn_sched_barrier(0);

      __builtin_amdgcn_s_setprio(1);
#pragma unroll
      for (int mi = 0; mi < 8; ++mi) {
        const int ra = (mi << 4) + l15;
        const bf16x8 af = *(const bf16x8*)
          &As[aCur + (ra << 5) + ((q ^ sw15) << 3)];
#pragma unroll
        for (int cg = 0; cg < 4; ++cg)
          acc[mi][cg] = __builtin_amdgcn_mfma_f32_16x16x32_bf16(
              af, bfr[cg], acc[mi][cg], 0, 0, 0);
      }
      __builtin_amdgcn_s_setprio(0);
    }
  }

  // ---- tail: ic = 15 (write B(15); A staged for taps<=6; no B loads) ----
  {
    __builtin_amdgcn_s_barrier();
    WAITV(4);
    writeB(Bs, tid, breg);
    WAITLGKM0;
#pragma unroll
    for (int tap = 0; tap < 9; ++tap) {
      if (tap < 8) { WAITV(2); } else { WAITV(0); }
      __builtin_amdgcn_s_barrier();
      __builtin_amdgcn_sched_barrier(0);

      const int ky = tap / 3, kx = tap % 3;
      const int aCur = (tap % 3) * AS_ELEMS;
      const int rbbase = (wv + ky) * 66 + kx;

      bf16x8 bfr[4];
#pragma unroll
      for (int cg = 0; cg < 4; ++cg) {
        const int rb = rbbase + cg * 16 + l15;
        bfr[cg] = *(const bf16x8*)&Bs[(rb << 5) + ((q ^ (rb & 3)) << 3)];
      }

      if (tap <= 6)
        stage_A(wb, As + ((tap + 2) % 3) * AS_ELEMS, 135 + tap + 2, o0, tid);

      __builtin_amdgcn_s_setprio(1);
#pragma unroll
      for (int mi = 0; mi < 8; ++mi) {
        const int ra = (mi << 4) + l15;
        const bf16x8 af = *(const bf16x8*)
          &As[aCur + (ra << 5) + ((q ^ sw15) << 3)];
#pragma unroll
        for (int cg = 0; cg < 4; ++cg)
          acc[mi][cg] = __builtin_amdgcn_mfma_f32_16x16x32_bf16(
              af, bfr[cg], acc[mi][cg], 0, 0, 0);
      }
      __builtin_amdgcn_s_setprio(0);
    }
  }

  // epilogue: out = sig[b][o] * acc + bias[o]
  const float* sigrow = sig + (size_t)b * COUT;
  const int y = y0 + wv;
#pragma unroll
  for (int mi = 0; mi < 8; ++mi) {
#pragma unroll
    for (int rg = 0; rg < 4; ++rg) {
      const int o = o0 + (mi << 4) + (q << 2) + rg;
      const float sgv = sigrow[o];
      const float bv  = bias[o];
      const size_t base = (((size_t)b * COUT + o) * HW_ + y) * HW_;
#pragma unroll
      for (int cg = 0; cg < 4; ++cg)
        out[base + (cg << 4) + l15] = acc[mi][cg][rg] * sgv + bv;
    }
  }
}

// ---------------------------------------------------------------------------
extern "C" void kernel_launch(void* const* d_in, const int* in_sizes, int n_in,
                              void* d_out, int out_size, void* d_ws, size_t ws_size,
                              hipStream_t stream) {
  const float* x    = (const float*)d_in[0];   // [16][512][64][64] fp32
  const float* s    = (const float*)d_in[1];   // [16][512] fp32
  const float* w    = (const float*)d_in[2];   // [512][512][3][3] fp32
  const float* bias = (const float*)d_in[3];   // [512] fp32
  float* out = (float*)d_out;                  // [16][512][64][64] fp32

  u16* xh    = (u16*)d_ws;                     // padded NHWC bf16 (x*C*s)
  u16* wbf   = xh + XH_ELEMS;                  // raw bf16 weights, MFMA layout
  float* sig = (float*)(wbf + WBF_ELEMS);      // [16][512] demod scales

  zero_border<<<(B_ * 260 * 64 + 255) / 256, 256, 0, stream>>>(xh);
  transpose_x<<<dim3(8, 32, 16), 256, 0, stream>>>(x, s, xh);
  sigma_kernel<<<512, 256, 0, stream>>>(w, s, sig);
  wlayout<<<256, 256, 0, stream>>>(w, wbf);
  modconv_mfma<<<1024, 256, 0, stream>>>(xh, wbf, sig, bias, out);
}

// Round 7
// 632.187 us; speedup vs baseline: 1.1172x; 1.1172x over previous
//
#include <hip/hip_runtime.h>
#include <cstdint>

typedef unsigned short u16;
typedef __bf16 bf16x8 __attribute__((ext_vector_type(8)));
typedef float f32x4 __attribute__((ext_vector_type(4)));

// Problem constants
#define B_    16
#define CIN   512
#define COUT  512
#define HW_   64
#define PW    66            // padded width/height
#define XH_ELEMS  ((size_t)B_*PW*PW*CIN)             // 35,684,352 u16 (71.4 MB)
#define WBF_ALLOC ((size_t)145*COUT*32)              // 144 phases + 1 pad phase

__device__ __forceinline__ u16 f2bf(float f) {
  union { float f; unsigned int u; } c; c.f = f;
  unsigned int u = c.u + 0x7fffu + ((c.u >> 16) & 1u);   // RNE
  return (u16)(u >> 16);
}

// async global->LDS, 16B per lane; dest must be wave-uniform-base + lane*16
__device__ __forceinline__ void async16(const void* g, void* l) {
  __builtin_amdgcn_global_load_lds(
      (__attribute__((address_space(1))) unsigned int*)(uintptr_t)g,
      (__attribute__((address_space(3))) unsigned int*)(uintptr_t)l,
      16, 0, 0);
}

// ---------------------------------------------------------------------------
// Kernel 1: zero the padding border of xh[b][66][66][512]
__global__ __launch_bounds__(256) void zero_border(u16* __restrict__ xh) {
  int g = blockIdx.x * 256 + threadIdx.x;
  if (g >= B_ * 260 * 64) return;
  int c8 = g & 63;
  int t  = g >> 6;             // 0 .. 16*260-1
  int b  = t / 260;
  int p  = t - b * 260;
  int rp, cp;
  if (p < 66)       { rp = 0;      cp = p; }
  else if (p < 132) { rp = 65;     cp = p - 66; }
  else {
    int q = p - 132;           // 0..127
    if (q < 64) { rp = q + 1;  cp = 0; }
    else        { rp = q - 63; cp = 65; }
  }
  u16* dst = xh + ((((size_t)b * PW + rp) * PW + cp) << 9) + (c8 << 3);
  *(uint4*)dst = make_uint4(0u, 0u, 0u, 0u);
}

// ---------------------------------------------------------------------------
// Kernel 2: fp32 NCHW -> bf16 padded NHWC, fusing the modulation scale:
// xh[b][y+1][x+1][i] = bf16( x[b][i][y][x] * C_EQ * s[b][i] ).
__global__ __launch_bounds__(256) void transpose_x(const float* __restrict__ x,
                                                   const float* __restrict__ s,
                                                   u16* __restrict__ xh) {
  const int t   = threadIdx.x;
  const int c8  = t & 7;             // 8-channel group
  const int xq  = (t >> 3) & 15;     // x quad
  const int y01 = t >> 7;            // row within pair
  const int i0  = blockIdx.x * 64;
  const int y   = blockIdx.y * 2 + y01;
  const int b   = blockIdx.z;

  const float C_EQ = 1.4731391e-2f;                 // 1/sqrt(512*9)
  const float4 sA = *(const float4*)(s + (size_t)b * CIN + i0 + c8 * 8);
  const float4 sB = *(const float4*)(s + (size_t)b * CIN + i0 + c8 * 8 + 4);
  float cs[8] = {C_EQ * sA.x, C_EQ * sA.y, C_EQ * sA.z, C_EQ * sA.w,
                 C_EQ * sB.x, C_EQ * sB.y, C_EQ * sB.z, C_EQ * sB.w};

  float4 v[8];
#pragma unroll
  for (int k = 0; k < 8; ++k) {
    const int ci = i0 + c8 * 8 + k;
    v[k] = *(const float4*)(
        x + ((((size_t)b * CIN + ci) * HW_ + y) * HW_) + xq * 4);
  }
#pragma unroll
  for (int j = 0; j < 4; ++j) {
    const int xx = xq * 4 + j;
    u16 oc[8];
#pragma unroll
    for (int k = 0; k < 8; ++k) oc[k] = f2bf(v[k][j] * cs[k]);
    u16* dst = xh + ((((size_t)b * PW + (y + 1)) * PW + (xx + 1)) << 9)
                  + i0 + c8 * 8;
    *(uint4*)dst = *(uint4*)oc;
  }
}

// ---------------------------------------------------------------------------
// Kernel 3a: demod sigma.  One block per o; 16-batch dot in one pass.
__global__ __launch_bounds__(256) void sigma_kernel(const float* __restrict__ w,
                                                    const float* __restrict__ s,
                                                    float* __restrict__ sig) {
  __shared__ float row[CIN * 9];       // 18,432 B
  __shared__ float part[16][4];

  const int o   = blockIdx.x;
  const int tid = threadIdx.x;
  const int wv  = tid >> 6;
  const int lane = tid & 63;
  const float* wrow = w + (size_t)o * (CIN * 9);

#pragma unroll
  for (int it = 0; it < 5; ++it) {
    const int c = it * 256 + tid;
    if (c < 1152) *(float4*)&row[c * 4] = *(const float4*)(wrow + c * 4);
  }
  __syncthreads();

  float q0 = 0.f, q1 = 0.f;
#pragma unroll
  for (int tt = 0; tt < 9; ++tt) {
    const float a = row[(2 * tid) * 9 + tt];
    const float c = row[(2 * tid + 1) * 9 + tt];
    q0 += a * a; q1 += c * c;
  }

  const float C_EQ = 1.4731391e-2f;                 // 1/sqrt(512*9)
#pragma unroll
  for (int b = 0; b < 16; ++b) {
    const float2 sv = *(const float2*)(s + (size_t)b * CIN + 2 * tid);
    float a = q0 * sv.x * sv.x + q1 * sv.y * sv.y;
#pragma unroll
    for (int off = 32; off > 0; off >>= 1) a += __shfl_xor(a, off, 64);
    if (lane == 0) part[b][wv] = a;
  }
  __syncthreads();
  if (tid < 16) {
    const float tot = part[tid][0] + part[tid][1] + part[tid][2] + part[tid][3];
    sig[(size_t)tid * COUT + o] = rsqrtf(tot * (C_EQ * C_EQ) + 1e-8f);
  }
}

// ---------------------------------------------------------------------------
// Kernel 3b: raw-weight layout transform (batch-independent).
// wbf[icc][tap][o][ich] = bf16(w[o][icc*32+ich][tap]).  4.7 MB, L2-resident.
__global__ __launch_bounds__(256) void wlayout(const float* __restrict__ w,
                                               u16* __restrict__ wbf) {
  __shared__ float wld[288][33];     // 38,016 B, transposed slab

  const int tid = threadIdx.x;
  const int icc = blockIdx.x & 15;
  const int oh  = blockIdx.x >> 4;   // 0..15
  const int o0  = oh << 5;           // 32 outputs per block

#pragma unroll
  for (int it = 0; it < 9; ++it) {
    const int c   = it * 256 + tid;      // 0..2303
    const int ol  = c / 72;
    const int col = c - ol * 72;
    const float4 v = *(const float4*)(
        w + (size_t)(o0 + ol) * (CIN * 9) + icc * 288 + col * 4);
#pragma unroll
    for (int j2 = 0; j2 < 4; ++j2) wld[col * 4 + j2][ol] = v[j2];
  }
  __syncthreads();

  const int ol = tid >> 3;
  const int g4 = tid & 7;
#pragma unroll
  for (int tap = 0; tap < 9; ++tap) {
    u16 oc[4];
#pragma unroll
    for (int kk = 0; kk < 4; ++kk)
      oc[kk] = f2bf(wld[(g4 * 4 + kk) * 9 + tap][ol]);
    *(uint2*)(wbf + (((size_t)(icc * 9 + tap) * COUT) + o0 + ol) * 32 + g4 * 4)
        = *(uint2*)oc;
  }
}

// ---------------------------------------------------------------------------
// Kernel 4: implicit-GEMM conv, round 7: A-OPERAND DIRECT FROM GLOBAL.
//   wbf is 4.7 MB, L2/L3-resident, and its MFMA layout makes each fragment a
//   perfectly-coalesced 1 KB wave read -> no LDS staging for A at all.
//   A fragments double-buffered in registers, one tap ahead (compiler-managed
//   waitcnts; no inline asm).  B stays in LDS (9-tap reuse), double-buffered
//   per ic-chunk, staged via async16 during taps 0..3.
//   Barriers: ONE per chunk (16 total vs 144) -- the 9-tap body is a single
//   straight-line region the compiler can software-pipeline freely.
//   VGPR: acc 128 + aC/aN 64 + temps  (launch_bounds(256,2): budget 256,
//   8-waves/CU tier; spill watch = WRITE_SIZE).
#define BROWS    (6 * 66)              // 396 rows per B buffer
#define BS_ELEMS (BROWS * 32)          // 12672 u16 (25.3 KB) per buffer

__device__ __forceinline__ void stage_B_slice(const u16* __restrict__ xb,
                                              u16* dst, int ic, int y0,
                                              int tid, int slice) {
  // 25.3 KB = 1584 chunks = 8 slices x 198.  XOR bank-swizzle applied via
  // pre-swizzled GLOBAL source + linear LDS dest (rule: both sides).
  if (tid < 198) {
    const int id   = slice * 198 + tid;
    const int row  = id >> 2;                  // rr*66+cc pixel in window
    const int slot = (id & 3) ^ (row & 3);
    async16(xb + ((size_t)y0 * PW + row) * CIN + ic * 32 + slot * 8,
            dst + id * 8);
  }
}

__global__ __launch_bounds__(256, 2) void modconv_mfma(const u16* __restrict__ xh,
                                                       const u16* __restrict__ wbf,
                                                       const float* __restrict__ sig,
                                                       const float* __restrict__ bias,
                                                       float* __restrict__ out) {
  __shared__ u16 Bs[2 * BS_ELEMS];     // 49.5 KB [buf][row][ch]

  const int tid  = threadIdx.x;
  const int lane = tid & 63;
  const int wv   = tid >> 6;           // wave's output row within 4-row tile
  const int l15  = lane & 15;
  const int q    = lane >> 4;          // k-quad 0..3

  // XCD-aware bijective swizzle: 1024 blocks = 8 XCDs x 128.
  const int lin     = blockIdx.x;
  const int logical = ((lin & 7) << 7) + (lin >> 3);
  const int yt = logical & 15;
  const int ot = (logical >> 4) & 3;
  const int b  = logical >> 6;
  const int y0 = yt << 2;              // 4 output rows per block
  const int o0 = ot << 7;              // 128 outputs per block

  const u16* xb = xh + (size_t)b * (PW * PW * CIN);
  // per-lane A base: fragment (mi) address = abase + phase*COUT*32 + mi*16*32
  const u16* abase = wbf + ((size_t)o0 + l15) * 32 + q * 8;

  f32x4 acc[8][4];
#pragma unroll
  for (int mi = 0; mi < 8; ++mi)
#pragma unroll
    for (int cg = 0; cg < 4; ++cg) acc[mi][cg] = (f32x4){0.f, 0.f, 0.f, 0.f};

  // prologue: stage B(0) (8 slices), load A(phase 0) fragments to registers
#pragma unroll
  for (int sl = 0; sl < 8; ++sl) stage_B_slice(xb, Bs, 0, y0, tid, sl);
  bf16x8 aC[8];
#pragma unroll
  for (int mi = 0; mi < 8; ++mi)
    aC[mi] = *(const bf16x8*)(abase + (size_t)(mi * 16) * 32);
  __syncthreads();                     // drains vmcnt: B(0) visible, aC landed

  for (int ic = 0; ic < 16; ++ic) {
    const int bOff = (ic & 1) * BS_ELEMS;
    const int bNxt = BS_ELEMS - bOff;
    const int stageNext = (ic < 15);
#pragma unroll
    for (int tap = 0; tap < 9; ++tap) {
      const int ky = tap / 3, kx = tap % 3;
      const int rbbase = (wv + ky) * 66 + kx;

      // B fragments from LDS (swizzled read)
      bf16x8 bfr[4];
#pragma unroll
      for (int cg = 0; cg < 4; ++cg) {
        const int rb = rbbase + cg * 16 + l15;
        bfr[cg] = *(const bf16x8*)&Bs[bOff + (rb << 5) + ((q ^ (rb & 3)) << 3)];
      }

      // next-tap A fragments, straight from global (L2-resident, coalesced).
      // Last iteration (phase 144) reads the pad phase -- loaded, never used.
      const u16* ap = abase + (size_t)(ic * 9 + tap + 1) * (COUT * 32);
      bf16x8 aN[8];
#pragma unroll
      for (int mi = 0; mi < 8; ++mi)
        aN[mi] = *(const bf16x8*)(ap + (size_t)(mi * 16) * 32);

      // stage next chunk's B window early (slices 0..7 over taps 0..3)
      if (stageNext && tap < 4) {
        stage_B_slice(xb, Bs + bNxt, ic + 1, y0, tid, 2 * tap);
        stage_B_slice(xb, Bs + bNxt, ic + 1, y0, tid, 2 * tap + 1);
      }

      __builtin_amdgcn_s_setprio(1);
#pragma unroll
      for (int mi = 0; mi < 8; ++mi)
#pragma unroll
        for (int cg = 0; cg < 4; ++cg)
          acc[mi][cg] = __builtin_amdgcn_mfma_f32_16x16x32_bf16(
              aC[mi], bfr[cg], acc[mi][cg], 0, 0, 0);
      __builtin_amdgcn_s_setprio(0);

#pragma unroll
      for (int mi = 0; mi < 8; ++mi) aC[mi] = aN[mi];   // SSA rename, no copy
    }
    __syncthreads();                   // chunk boundary: B dbuf swap safe
  }

  // epilogue: out = sig[b][o] * acc + bias[o]
  const float* sigrow = sig + (size_t)b * COUT;
  const int y = y0 + wv;
#pragma unroll
  for (int mi = 0; mi < 8; ++mi) {
#pragma unroll
    for (int rg = 0; rg < 4; ++rg) {
      const int o = o0 + (mi << 4) + (q << 2) + rg;
      const float sgv = sigrow[o];
      const float bv  = bias[o];
      const size_t base = (((size_t)b * COUT + o) * HW_ + y) * HW_;
#pragma unroll
      for (int cg = 0; cg < 4; ++cg)
        out[base + (cg << 4) + l15] = acc[mi][cg][rg] * sgv + bv;
    }
  }
}

// ---------------------------------------------------------------------------
extern "C" void kernel_launch(void* const* d_in, const int* in_sizes, int n_in,
                              void* d_out, int out_size, void* d_ws, size_t ws_size,
                              hipStream_t stream) {
  const float* x    = (const float*)d_in[0];   // [16][512][64][64] fp32
  const float* s    = (const float*)d_in[1];   // [16][512] fp32
  const float* w    = (const float*)d_in[2];   // [512][512][3][3] fp32
  const float* bias = (const float*)d_in[3];   // [512] fp32
  float* out = (float*)d_out;                  // [16][512][64][64] fp32

  u16* xh    = (u16*)d_ws;                     // padded NHWC bf16 (x*C*s)
  u16* wbf   = xh + XH_ELEMS;                  // raw bf16 weights, MFMA layout
  float* sig = (float*)(wbf + WBF_ALLOC);      // [16][512] demod scales

  zero_border<<<(B_ * 260 * 64 + 255) / 256, 256, 0, stream>>>(xh);
  transpose_x<<<dim3(8, 32, 16), 256, 0, stream>>>(x, s, xh);
  sigma_kernel<<<512, 256, 0, stream>>>(w, s, sig);
  wlayout<<<256, 256, 0, stream>>>(w, wbf);
  modconv_mfma<<<1024, 256, 0, stream>>>(xh, wbf, sig, bias, out);
}

// Round 8
// 459.688 us; speedup vs baseline: 1.5364x; 1.3753x over previous
//
#include <hip/hip_runtime.h>
#include <cstdint>

typedef unsigned short u16;
typedef __bf16 bf16x8 __attribute__((ext_vector_type(8)));
typedef float f32x4 __attribute__((ext_vector_type(4)));

// Problem constants
#define B_    16
#define CIN   512
#define COUT  512
#define HW_   64
#define PW    66            // padded width/height
#define XH_ELEMS  ((size_t)B_*PW*PW*CIN)             // 35,684,352 u16 (71.4 MB)
#define WBF_ELEMS ((size_t)16*9*COUT*32)             //  2,359,296 u16 (4.7 MB)

#define WAITV(N) asm volatile("s_waitcnt vmcnt(" #N ")" ::: "memory")

__device__ __forceinline__ u16 f2bf(float f) {
  union { float f; unsigned int u; } c; c.f = f;
  unsigned int u = c.u + 0x7fffu + ((c.u >> 16) & 1u);   // RNE
  return (u16)(u >> 16);
}

// async global->LDS, 16B per lane; dest must be wave-uniform-base + lane*16
__device__ __forceinline__ void async16(const void* g, void* l) {
  __builtin_amdgcn_global_load_lds(
      (__attribute__((address_space(1))) unsigned int*)(uintptr_t)g,
      (__attribute__((address_space(3))) unsigned int*)(uintptr_t)l,
      16, 0, 0);
}

// ---------------------------------------------------------------------------
// Kernel 1: zero the padding border of xh[b][66][66][512]
__global__ __launch_bounds__(256) void zero_border(u16* __restrict__ xh) {
  int g = blockIdx.x * 256 + threadIdx.x;
  if (g >= B_ * 260 * 64) return;
  int c8 = g & 63;
  int t  = g >> 6;             // 0 .. 16*260-1
  int b  = t / 260;
  int p  = t - b * 260;
  int rp, cp;
  if (p < 66)       { rp = 0;      cp = p; }
  else if (p < 132) { rp = 65;     cp = p - 66; }
  else {
    int q = p - 132;           // 0..127
    if (q < 64) { rp = q + 1;  cp = 0; }
    else        { rp = q - 63; cp = 65; }
  }
  u16* dst = xh + ((((size_t)b * PW + rp) * PW + cp) << 9) + (c8 << 3);
  *(uint4*)dst = make_uint4(0u, 0u, 0u, 0u);
}

// ---------------------------------------------------------------------------
// Kernel 2: fp32 NCHW -> bf16 padded NHWC, FUSING the modulation scale:
// xh[b][y+1][x+1][i] = bf16( x[b][i][y][x] * C_EQ * s[b][i] ).
__global__ __launch_bounds__(256) void transpose_x(const float* __restrict__ x,
                                                   const float* __restrict__ s,
                                                   u16* __restrict__ xh) {
  const int t   = threadIdx.x;
  const int c8  = t & 7;             // 8-channel group
  const int xq  = (t >> 3) & 15;     // x quad
  const int y01 = t >> 7;            // row within pair
  const int i0  = blockIdx.x * 64;
  const int y   = blockIdx.y * 2 + y01;
  const int b   = blockIdx.z;

  const float C_EQ = 1.4731391e-2f;                 // 1/sqrt(512*9)
  const float4 sA = *(const float4*)(s + (size_t)b * CIN + i0 + c8 * 8);
  const float4 sB = *(const float4*)(s + (size_t)b * CIN + i0 + c8 * 8 + 4);
  float cs[8] = {C_EQ * sA.x, C_EQ * sA.y, C_EQ * sA.z, C_EQ * sA.w,
                 C_EQ * sB.x, C_EQ * sB.y, C_EQ * sB.z, C_EQ * sB.w};

  float4 v[8];
#pragma unroll
  for (int k = 0; k < 8; ++k) {
    const int ci = i0 + c8 * 8 + k;
    v[k] = *(const float4*)(
        x + ((((size_t)b * CIN + ci) * HW_ + y) * HW_) + xq * 4);
  }
#pragma unroll
  for (int j = 0; j < 4; ++j) {
    const int xx = xq * 4 + j;
    u16 oc[8];
#pragma unroll
    for (int k = 0; k < 8; ++k) oc[k] = f2bf(v[k][j] * cs[k]);
    u16* dst = xh + ((((size_t)b * PW + (y + 1)) * PW + (xx + 1)) << 9)
                  + i0 + c8 * 8;
    *(uint4*)dst = *(uint4*)oc;
  }
}

// ---------------------------------------------------------------------------
// Kernel 3a: demod sigma.  One block per o; 16-batch dot in one pass.
__global__ __launch_bounds__(256) void sigma_kernel(const float* __restrict__ w,
                                                    const float* __restrict__ s,
                                                    float* __restrict__ sig) {
  __shared__ float row[CIN * 9];       // 18,432 B
  __shared__ float part[16][4];

  const int o   = blockIdx.x;
  const int tid = threadIdx.x;
  const int wv  = tid >> 6;
  const int lane = tid & 63;
  const float* wrow = w + (size_t)o * (CIN * 9);

#pragma unroll
  for (int it = 0; it < 5; ++it) {
    const int c = it * 256 + tid;
    if (c < 1152) *(float4*)&row[c * 4] = *(const float4*)(wrow + c * 4);
  }
  __syncthreads();

  float q0 = 0.f, q1 = 0.f;
#pragma unroll
  for (int tt = 0; tt < 9; ++tt) {
    const float a = row[(2 * tid) * 9 + tt];
    const float c = row[(2 * tid + 1) * 9 + tt];
    q0 += a * a; q1 += c * c;
  }

  const float C_EQ = 1.4731391e-2f;                 // 1/sqrt(512*9)
#pragma unroll
  for (int b = 0; b < 16; ++b) {
    const float2 sv = *(const float2*)(s + (size_t)b * CIN + 2 * tid);
    float a = q0 * sv.x * sv.x + q1 * sv.y * sv.y;
#pragma unroll
    for (int off = 32; off > 0; off >>= 1) a += __shfl_xor(a, off, 64);
    if (lane == 0) part[b][wv] = a;
  }
  __syncthreads();
  if (tid < 16) {
    const float tot = part[tid][0] + part[tid][1] + part[tid][2] + part[tid][3];
    sig[(size_t)tid * COUT + o] = rsqrtf(tot * (C_EQ * C_EQ) + 1e-8f);
  }
}

// ---------------------------------------------------------------------------
// Kernel 3b: raw-weight layout transform (batch-independent).
// wbf[icc][tap][o][ich] = bf16(w[o][icc*32+ich][tap]).  4.7 MB, L2-resident.
__global__ __launch_bounds__(256) void wlayout(const float* __restrict__ w,
                                               u16* __restrict__ wbf) {
  __shared__ float wld[288][33];     // 38,016 B, transposed slab

  const int tid = threadIdx.x;
  const int icc = blockIdx.x & 15;
  const int oh  = blockIdx.x >> 4;   // 0..15
  const int o0  = oh << 5;           // 32 outputs per block

#pragma unroll
  for (int it = 0; it < 9; ++it) {
    const int c   = it * 256 + tid;      // 0..2303
    const int ol  = c / 72;
    const int col = c - ol * 72;
    const float4 v = *(const float4*)(
        w + (size_t)(o0 + ol) * (CIN * 9) + icc * 288 + col * 4);
#pragma unroll
    for (int j2 = 0; j2 < 4; ++j2) wld[col * 4 + j2][ol] = v[j2];
  }
  __syncthreads();

  const int ol = tid >> 3;
  const int g4 = tid & 7;
#pragma unroll
  for (int tap = 0; tap < 9; ++tap) {
    u16 oc[4];
#pragma unroll
    for (int kk = 0; kk < 4; ++kk)
      oc[kk] = f2bf(wld[(g4 * 4 + kk) * 9 + tap][ol]);
    *(uint2*)(wbf + (((size_t)(icc * 9 + tap) * COUT) + o0 + ol) * 32 + g4 * 4)
        = *(uint2*)oc;
  }
}

// ---------------------------------------------------------------------------
// Kernel 4: implicit-GEMM conv, counted-vmcnt pipeline (T4).  This is the
// round-5 VERIFIED body (239.2 us, MfmaUtil 58.8%): A triple-buffered in LDS
// staged 2 phases ahead; B double-buffered per ic-chunk, staged in 8 slices
// over taps 0..7; one raw s_barrier + counted s_waitcnt per tap; shared
// raw-weight A (factorized modulation), sig applied in the epilogue.
#define AS_ELEMS (128 * 32)            // 4096 u16 per A buffer (8 KB)
#define BROWS    (6 * 66)              // 396 rows per B buffer
#define BS_ELEMS (BROWS * 32)          // 12672 u16 per B buffer (25.3 KB)

__device__ __forceinline__ void stage_A(const u16* __restrict__ wb,
                                        u16* dst, int phase, int o0, int tid) {
  const u16* asrc = wb + ((size_t)phase * COUT + o0) * 32;
#pragma unroll
  for (int t = 0; t < 2; ++t) {
    const int id   = t * 256 + tid;
    const int row  = id >> 2;
    const int slot = (id & 3) ^ (row & 3);
    async16(asrc + row * 32 + slot * 8, dst + id * 8);
  }
}

__device__ __forceinline__ void stage_B_slice(const u16* __restrict__ xb,
                                              u16* dst, int ic, int y0,
                                              int tid, int slice) {
  if (tid < 198) {
    const int id   = slice * 198 + tid;
    const int row  = id >> 2;                  // rr*66+cc pixel in window
    const int slot = (id & 3) ^ (row & 3);
    async16(xb + ((size_t)y0 * PW + row) * CIN + ic * 32 + slot * 8,
            dst + id * 8);
  }
}

__global__ __launch_bounds__(256, 2) void modconv_mfma(const u16* __restrict__ xh,
                                                       const u16* __restrict__ wbf,
                                                       const float* __restrict__ sig,
                                                       const float* __restrict__ bias,
                                                       float* __restrict__ out) {
  __shared__ u16 As[3 * AS_ELEMS];     // 24 KB   [buf][o_local][ch]
  __shared__ u16 Bs[2 * BS_ELEMS];     // 50.7 KB [buf][row][ch]

  const int tid  = threadIdx.x;
  const int lane = tid & 63;
  const int wv   = tid >> 6;
  const int l15  = lane & 15;
  const int q    = lane >> 4;
  const int sw15 = l15 & 3;

  const int lin     = blockIdx.x;
  const int logical = ((lin & 7) << 7) + (lin >> 3);
  const int yt = logical & 15;
  const int ot = (logical >> 4) & 3;
  const int b  = logical >> 6;
  const int y0 = yt << 2;
  const int o0 = ot << 7;

  const u16* xb = xh + (size_t)b * (PW * PW * CIN);
  const u16* wb = wbf;                 // shared across batches

  f32x4 acc[8][4];
#pragma unroll
  for (int mi = 0; mi < 8; ++mi)
#pragma unroll
    for (int cg = 0; cg < 4; ++cg) acc[mi][cg] = (f32x4){0.f, 0.f, 0.f, 0.f};

#pragma unroll
  for (int sl = 0; sl < 8; ++sl) stage_B_slice(xb, Bs, 0, y0, tid, sl);
  stage_A(wb, As, 0, o0, tid);
  stage_A(wb, As + AS_ELEMS, 1, o0, tid);

  for (int ic = 0; ic < 15; ++ic) {
    const int bOff = (ic & 1) * BS_ELEMS;
    const int bNxt = BS_ELEMS - bOff;
#pragma unroll
    for (int tap = 0; tap < 9; ++tap) {
      if (tap == 0) { WAITV(2); } else { WAITV(3); }
      __builtin_amdgcn_s_barrier();
      __builtin_amdgcn_sched_barrier(0);

      const int ky = tap / 3, kx = tap % 3;
      const int aCur = (tap % 3) * AS_ELEMS;
      const int aDst = ((tap + 2) % 3) * AS_ELEMS;
      const int rbbase = (wv + ky) * 66 + kx;

      bf16x8 bfr[4];
#pragma unroll
      for (int cg = 0; cg < 4; ++cg) {
        const int rb = rbbase + cg * 16 + l15;
        bfr[cg] = *(const bf16x8*)
          &Bs[bOff + (rb << 5) + ((q ^ (rb & 3)) << 3)];
      }

      stage_A(wb, As + aDst, ic * 9 + tap + 2, o0, tid);
      if (tap < 8) stage_B_slice(xb, Bs + bNxt, ic + 1, y0, tid, tap);

      __builtin_amdgcn_s_setprio(1);
#pragma unroll
      for (int mi = 0; mi < 8; ++mi) {
        const int ra = (mi << 4) + l15;
        const bf16x8 af = *(const bf16x8*)
          &As[aCur + (ra << 5) + ((q ^ sw15) << 3)];
#pragma unroll
        for (int cg = 0; cg < 4; ++cg)
          acc[mi][cg] = __builtin_amdgcn_mfma_f32_16x16x32_bf16(
              af, bfr[cg], acc[mi][cg], 0, 0, 0);
      }
      __builtin_amdgcn_s_setprio(0);
    }
  }

  {
    const int bOff = BS_ELEMS;
#pragma unroll
    for (int tap = 0; tap < 9; ++tap) {
      if (tap < 8) { WAITV(2); } else { WAITV(0); }
      __builtin_amdgcn_s_barrier();
      __builtin_amdgcn_sched_barrier(0);

      const int ky = tap / 3, kx = tap % 3;
      const int aCur = (tap % 3) * AS_ELEMS;
      const int rbbase = (wv + ky) * 66 + kx;

      bf16x8 bfr[4];
#pragma unroll
      for (int cg = 0; cg < 4; ++cg) {
        const int rb = rbbase + cg * 16 + l15;
        bfr[cg] = *(const bf16x8*)
          &Bs[bOff + (rb << 5) + ((q ^ (rb & 3)) << 3)];
      }

      if (tap <= 6)
        stage_A(wb, As + ((tap + 2) % 3) * AS_ELEMS, 135 + tap + 2, o0, tid);

      __builtin_amdgcn_s_setprio(1);
#pragma unroll
      for (int mi = 0; mi < 8; ++mi) {
        const int ra = (mi << 4) + l15;
        const bf16x8 af = *(const bf16x8*)
          &As[aCur + (ra << 5) + ((q ^ sw15) << 3)];
#pragma unroll
        for (int cg = 0; cg < 4; ++cg)
          acc[mi][cg] = __builtin_amdgcn_mfma_f32_16x16x32_bf16(
              af, bfr[cg], acc[mi][cg], 0, 0, 0);
      }
      __builtin_amdgcn_s_setprio(0);
    }
  }

  // epilogue: out = sig[b][o] * acc + bias[o]
  const float* sigrow = sig + (size_t)b * COUT;
  const int y = y0 + wv;
#pragma unroll
  for (int mi = 0; mi < 8; ++mi) {
#pragma unroll
    for (int rg = 0; rg < 4; ++rg) {
      const int o = o0 + (mi << 4) + (q << 2) + rg;
      const float sgv = sigrow[o];
      const float bv  = bias[o];
      const size_t base = (((size_t)b * COUT + o) * HW_ + y) * HW_;
#pragma unroll
      for (int cg = 0; cg < 4; ++cg)
        out[base + (cg << 4) + l15] = acc[mi][cg][rg] * sgv + bv;
    }
  }
}

// ---------------------------------------------------------------------------
extern "C" void kernel_launch(void* const* d_in, const int* in_sizes, int n_in,
                              void* d_out, int out_size, void* d_ws, size_t ws_size,
                              hipStream_t stream) {
  const float* x    = (const float*)d_in[0];   // [16][512][64][64] fp32
  const float* s    = (const float*)d_in[1];   // [16][512] fp32
  const float* w    = (const float*)d_in[2];   // [512][512][3][3] fp32
  const float* bias = (const float*)d_in[3];   // [512] fp32
  float* out = (float*)d_out;                  // [16][512][64][64] fp32

  u16* xh    = (u16*)d_ws;                     // padded NHWC bf16 (x*C*s)
  u16* wbf   = xh + XH_ELEMS;                  // raw bf16 weights, MFMA layout
  float* sig = (float*)(wbf + WBF_ELEMS);      // [16][512] demod scales

  zero_border<<<(B_ * 260 * 64 + 255) / 256, 256, 0, stream>>>(xh);
  transpose_x<<<dim3(8, 32, 16), 256, 0, stream>>>(x, s, xh);
  sigma_kernel<<<512, 256, 0, stream>>>(w, s, sig);
  wlayout<<<256, 256, 0, stream>>>(w, wbf);
  modconv_mfma<<<1024, 256, 0, stream>>>(xh, wbf, sig, bias, out);
}